// Round 1
// 1377.245 us; speedup vs baseline: 1.0382x; 1.0382x over previous
//
#include <hip/hip_runtime.h>
#include <hip/hip_bf16.h>
#include <cstdint>
#include <cstddef>

// Inputs fp32, output fp32. Internal bf16 MFMA (m97 recipe: one-shot bf16
// convert/transpose passes, then global_load_lds-staged 128-tile GEMMs).
// R1: double-buffered LDS + counted vmcnt(4) prefetch pipeline in both GEMMs
// (raw s_barrier, no vmcnt(0) drain in steady state).

#define S_ 2048
#define B_ 4
#define H_ 2048
#define F_ 1408
#define F2_ 2816
#define E_ 8
#define T_ 8192

typedef float f32x4 __attribute__((ext_vector_type(4)));
typedef short s16x8 __attribute__((ext_vector_type(8)));

#define WAITV4 asm volatile("s_waitcnt vmcnt(4)" ::: "memory")
#define WAITV0 asm volatile("s_waitcnt vmcnt(0)" ::: "memory")
#define LGKM0  asm volatile("s_waitcnt lgkmcnt(0)" ::: "memory")
#define SB()   __builtin_amdgcn_s_barrier()
#define SCB()  __builtin_amdgcn_sched_barrier(0)

__device__ __forceinline__ unsigned short f2b(float f) {
  union { unsigned int i; float f; } v; v.f = f;
  unsigned int r = v.i + 0x7FFFu + ((v.i >> 16) & 1u);
  return (unsigned short)(r >> 16);
}
__device__ __forceinline__ unsigned int pkbf(float lo, float hi) {
  __hip_bfloat162 h2 = __float22bfloat162_rn(make_float2(lo, hi));
  union { __hip_bfloat162 v; unsigned int u; } c; c.v = h2; return c.u;
}
__device__ __forceinline__ void gld16(const unsigned short* gp, unsigned short* lp) {
  __builtin_amdgcn_global_load_lds(
      (const __attribute__((address_space(1))) unsigned int*)gp,
      (__attribute__((address_space(3))) unsigned int*)lp, 16, 0, 0);
}

// ---------------- workspace layout (bytes) ----------------
// 0       : int counts[8]; 32: cursor[8]; 64: offs[8]
// 128     : int   eidx[2T]
// 65664   : float ewt[2T]
// 131200  : int   rowlist[2T]
// 196736  : float rowwt[2T]
// 262272  : bf16  g[2T][F]            (46137344)
// 46399616: bf16  xb[T][H]            (33554432)   x cast, token layout
// 79954048: bf16  w1t[E][2F][H]       (92274688)   transposed (k-major)
// 172228736: bf16 w2t[E][H][F]        (46137344)   transposed (k-major)
// total ~218.4 MB

__global__ void zero_kernel(int* ws_i) {
  if (threadIdx.x < 16) ws_i[threadIdx.x] = 0;
}

__global__ __launch_bounds__(256) void cvt_kernel(
    const float* __restrict__ src, unsigned short* __restrict__ dst, int n8) {
  int i = blockIdx.x * 256 + threadIdx.x;
  if (i >= n8) return;
  f32x4 a = *(const f32x4*)(src + (size_t)i * 8);
  f32x4 b = *(const f32x4*)(src + (size_t)i * 8 + 4);
  uint4 u;
  u.x = pkbf(a[0], a[1]); u.y = pkbf(a[2], a[3]);
  u.z = pkbf(b[0], b[1]); u.w = pkbf(b[2], b[3]);
  *(uint4*)(dst + (size_t)i * 8) = u;
}

// src[e][r][c] fp32 -> dst[e][c][r] bf16.  64x64 tiles, dims % 64 == 0.
__global__ __launch_bounds__(256) void tcvt_kernel(
    const float* __restrict__ src, unsigned short* __restrict__ dst,
    int rows, int cols) {
  int e = blockIdx.z;
  int c0 = blockIdx.x * 64, r0 = blockIdx.y * 64;
  const float* s = src + (size_t)e * rows * cols;
  unsigned short* d = dst + (size_t)e * rows * cols;
  __shared__ unsigned short Lt[64][72];
  int tid = threadIdx.x;
  int cl = tid & 63, w = tid >> 6;
#pragma unroll
  for (int i = 0; i < 16; i++) {
    int r = w * 16 + i;
    Lt[cl][r] = f2b(s[(size_t)(r0 + r) * cols + c0 + cl]);
  }
  __syncthreads();
  int cc = tid >> 3, hc = tid & 7;
#pragma unroll
  for (int j = 0; j < 2; j++) {
    int c = cc + j * 32;
    *(uint4*)&d[(size_t)(c0 + c) * rows + r0 + hc * 8] = *(uint4*)&Lt[c][hc * 8];
  }
}

// one wave per token: fp32 logits over 8 experts, softmax, top-2
__global__ __launch_bounds__(256) void gate_kernel(
    const float* __restrict__ x, const float* __restrict__ wg,
    int* __restrict__ counts, int* __restrict__ eidx, float* __restrict__ ewt) {
  int wave = threadIdx.x >> 6, lane = threadIdx.x & 63;
  int t = blockIdx.x * 4 + wave;
  int b = t >> 11, s = t & (S_ - 1);
  const float* xrow = x + (size_t)(s * B_ + b) * H_;
  float acc[E_];
#pragma unroll
  for (int e = 0; e < E_; e++) acc[e] = 0.f;
  for (int h0 = lane * 4; h0 < H_; h0 += 256) {
    f32x4 xa = *(const f32x4*)(xrow + h0);
#pragma unroll
    for (int e = 0; e < E_; e++) {
      f32x4 wa = *(const f32x4*)(wg + e * H_ + h0);
      acc[e] += xa[0] * wa[0] + xa[1] * wa[1] + xa[2] * wa[2] + xa[3] * wa[3];
    }
  }
#pragma unroll
  for (int e = 0; e < E_; e++)
    for (int off = 32; off; off >>= 1) acc[e] += __shfl_xor(acc[e], off, 64);
  if (lane == 0) {
    float m = acc[0];
#pragma unroll
    for (int e = 1; e < E_; e++) m = fmaxf(m, acc[e]);
    float ex[E_], ssum = 0.f;
#pragma unroll
    for (int e = 0; e < E_; e++) { ex[e] = __expf(acc[e] - m); ssum += ex[e]; }
    float sc[E_];
#pragma unroll
    for (int e = 0; e < E_; e++) sc[e] = ex[e] / ssum;
    int i1 = 0;
#pragma unroll
    for (int e = 1; e < E_; e++) if (sc[e] > sc[i1]) i1 = e;
    int i2 = (i1 == 0) ? 1 : 0;
#pragma unroll
    for (int e = 0; e < E_; e++) if (e != i1 && sc[e] > sc[i2]) i2 = e;
    float wsum = sc[i1] + sc[i2] + 1e-20f;
    eidx[2 * t] = i1;     ewt[2 * t] = sc[i1] / wsum;
    eidx[2 * t + 1] = i2; ewt[2 * t + 1] = sc[i2] / wsum;
    atomicAdd(&counts[i1], 1);
    atomicAdd(&counts[i2], 1);
  }
}

__global__ void scan_kernel(const int* __restrict__ counts, int* __restrict__ offs) {
  if (threadIdx.x == 0) {
    int run = 0;
    for (int e = 0; e < E_; e++) { offs[e] = run; run += counts[e]; }
  }
}

__global__ void assign_kernel(const int* __restrict__ eidx, const float* __restrict__ ewt,
                              const int* __restrict__ offs, int* __restrict__ cursor,
                              int* __restrict__ rowlist, float* __restrict__ rowwt) {
  int t = blockIdx.x * 256 + threadIdx.x;
  if (t >= T_) return;
#pragma unroll
  for (int k = 0; k < 2; k++) {
    int e = eidx[2 * t + k];
    int pos = atomicAdd(&cursor[e], 1);
    int slot = offs[e] + pos;
    rowlist[slot] = t;
    rowwt[slot] = ewt[2 * t + k];
  }
}

// GEMM1 + swiglu. grid (rt=64, ft=22, e=8). Tile 128 rows x 64 f-pairs, BK=32,
// double-buffered (2 x 32-col K-tiles in flight, counted vmcnt).
__global__ __launch_bounds__(256) void gemm1_kernel(
    const unsigned short* __restrict__ xb, const unsigned short* __restrict__ w1t,
    const int* __restrict__ counts, const int* __restrict__ offs,
    const int* __restrict__ rowlist, unsigned short* __restrict__ g) {
  int e = blockIdx.z, ft = blockIdx.y, rt = blockIdx.x;
  int ne = counts[e];
  if (rt * 128 >= ne) return;
  int base = offs[e];

  __shared__ unsigned short aL[2][128 * 32];
  __shared__ unsigned short bLa[2][64 * 32];
  __shared__ unsigned short bLb[2][64 * 32];

  int tid = threadIdx.x;
  int lane = tid & 63, wave = tid >> 6;
  int wm = (wave & 1) * 64, wn = (wave >> 1) * 32;
  int quad = lane >> 4, l15 = lane & 15;

  // staging: chunk layout row = tid>>2 (+64), kchunk = tid&3 -> linear lane*16B
  int srow = tid >> 2, kc = tid & 3;
  int t0 = rowlist[base + min(rt * 128 + srow, ne - 1)];
  int t1 = rowlist[base + min(rt * 128 + 64 + srow, ne - 1)];
  const unsigned short* ap0 = xb + (size_t)((t0 & (S_ - 1)) * B_ + (t0 >> 11)) * H_ + kc * 8;
  const unsigned short* ap1 = xb + (size_t)((t1 & (S_ - 1)) * B_ + (t1 >> 11)) * H_ + kc * 8;
  const unsigned short* bpa = w1t + ((size_t)e * F2_ + ft * 64 + srow) * H_ + kc * 8;
  const unsigned short* bpb = bpa + (size_t)F_ * H_;

  f32x4 acc[2][4][2];
#pragma unroll
  for (int h2 = 0; h2 < 2; h2++)
    for (int i = 0; i < 4; i++)
      for (int j = 0; j < 2; j++) acc[h2][i][j] = (f32x4){0.f, 0.f, 0.f, 0.f};

#define G1STAGE(buf, kk) do {                                  \
    gld16(ap0 + (kk), &aL[buf][wave * 512]);                   \
    gld16(ap1 + (kk), &aL[buf][2048 + wave * 512]);            \
    gld16(bpa + (kk), &bLa[buf][wave * 512]);                  \
    gld16(bpb + (kk), &bLb[buf][wave * 512]); } while (0)

#define G1COMP(buf) do {                                                         \
    s16x8 af[4], vfa[2], vfb[2];                                                 \
    _Pragma("unroll")                                                            \
    for (int mi = 0; mi < 4; mi++)                                               \
      af[mi] = *(const s16x8*)&aL[buf][(wm + mi * 16 + l15) * 32 + quad * 8];    \
    _Pragma("unroll")                                                            \
    for (int ni = 0; ni < 2; ni++) {                                             \
      vfa[ni] = *(const s16x8*)&bLa[buf][(wn + ni * 16 + l15) * 32 + quad * 8];  \
      vfb[ni] = *(const s16x8*)&bLb[buf][(wn + ni * 16 + l15) * 32 + quad * 8];  \
    }                                                                            \
    LGKM0; SB(); SCB();                                                          \
    if (!lastp) { G1STAGE(buf, knext); }                                         \
    _Pragma("unroll")                                                            \
    for (int mi = 0; mi < 4; mi++)                                               \
      _Pragma("unroll")                                                          \
      for (int ni = 0; ni < 2; ni++) {                                           \
        acc[0][mi][ni] = __builtin_amdgcn_mfma_f32_16x16x32_bf16(af[mi], vfa[ni], acc[0][mi][ni], 0, 0, 0); \
        acc[1][mi][ni] = __builtin_amdgcn_mfma_f32_16x16x32_bf16(af[mi], vfb[ni], acc[1][mi][ni], 0, 0, 0); \
      } } while (0)

  G1STAGE(0, 0);
  G1STAGE(1, 32);

  for (int k0 = 0; k0 < H_; k0 += 64) {
    int lastp = (k0 + 64 >= H_);
    // sub-iter A: tile k0 in buf0; stage k0+64 -> buf0
    WAITV4; SB(); SCB();
    { int knext = k0 + 64; G1COMP(0); }
    // sub-iter B: tile k0+32 in buf1; stage k0+96 -> buf1
    if (lastp) { WAITV0; } else { WAITV4; }
    SB(); SCB();
    { int knext = k0 + 96; G1COMP(1); }
  }
#undef G1STAGE
#undef G1COMP

#pragma unroll
  for (int mi = 0; mi < 4; mi++)
#pragma unroll
    for (int ni = 0; ni < 2; ni++)
#pragma unroll
      for (int v = 0; v < 4; v++) {
        int row = wm + mi * 16 + quad * 4 + v;
        if (rt * 128 + row < ne) {
          int col = wn + ni * 16 + l15;
          float a = acc[0][mi][ni][v], bb = acc[1][mi][ni][v];
          float sg = a / (1.f + __expf(-a));
          g[(size_t)(base + rt * 128 + row) * F_ + ft * 64 + col] = f2b(sg * bb);
        }
      }
}

// GEMM2: out[token] += rowwt * (g[slot,:] @ W2t[e]^T).  grid (64, 16, 8). 128x128,
// BK=32, double-buffered counted-vmcnt pipeline.
__global__ __launch_bounds__(256) void gemm2_kernel(
    const unsigned short* __restrict__ g, const unsigned short* __restrict__ w2t,
    const int* __restrict__ counts, const int* __restrict__ offs,
    const int* __restrict__ rowlist, const float* __restrict__ rowwt,
    float* __restrict__ out) {
  int e = blockIdx.z, nt = blockIdx.y, rt = blockIdx.x;
  int ne = counts[e];
  if (rt * 128 >= ne) return;
  int base = offs[e];

  __shared__ unsigned short aL[2][128 * 32];
  __shared__ unsigned short bL[2][128 * 32];
  __shared__ float rwL[128];
  __shared__ int   toL[128];

  int tid = threadIdx.x;
  int lane = tid & 63, wave = tid >> 6;
  int wm = (wave & 1) * 64, wn = (wave >> 1) * 64;
  int quad = lane >> 4, l15 = lane & 15;

  int srow = tid >> 2, kc = tid & 3;
  int r0c = min(rt * 128 + srow, ne - 1);
  int r1c = min(rt * 128 + 64 + srow, ne - 1);
  const unsigned short* ap0 = g + (size_t)(base + r0c) * F_ + kc * 8;
  const unsigned short* ap1 = g + (size_t)(base + r1c) * F_ + kc * 8;
  const unsigned short* bp0 = w2t + ((size_t)e * H_ + nt * 128 + srow) * F_ + kc * 8;
  const unsigned short* bp1 = bp0 + (size_t)64 * F_;

  if (tid < 128) {
    int rr = min(rt * 128 + tid, ne - 1);
    rwL[tid] = rowwt[base + rr];
    int tk = rowlist[base + rr];
    toL[tid] = ((tk & (S_ - 1)) * B_ + (tk >> 11)) * H_;
  }

  f32x4 acc[4][4];
#pragma unroll
  for (int i = 0; i < 4; i++)
    for (int j = 0; j < 4; j++) acc[i][j] = (f32x4){0.f, 0.f, 0.f, 0.f};

#define G2STAGE(buf, kk) do {                                  \
    gld16(ap0 + (kk), &aL[buf][wave * 512]);                   \
    gld16(ap1 + (kk), &aL[buf][2048 + wave * 512]);            \
    gld16(bp0 + (kk), &bL[buf][wave * 512]);                   \
    gld16(bp1 + (kk), &bL[buf][2048 + wave * 512]); } while (0)

#define G2COMP(buf) do {                                                        \
    s16x8 af[4], bf[4];                                                         \
    _Pragma("unroll")                                                           \
    for (int mi = 0; mi < 4; mi++)                                              \
      af[mi] = *(const s16x8*)&aL[buf][(wm + mi * 16 + l15) * 32 + quad * 8];   \
    _Pragma("unroll")                                                           \
    for (int ni = 0; ni < 4; ni++)                                              \
      bf[ni] = *(const s16x8*)&bL[buf][(wn + ni * 16 + l15) * 32 + quad * 8];   \
    LGKM0; SB(); SCB();                                                         \
    if (!lastp) { G2STAGE(buf, knext); }                                        \
    _Pragma("unroll")                                                           \
    for (int mi = 0; mi < 4; mi++)                                              \
      _Pragma("unroll")                                                         \
      for (int ni = 0; ni < 4; ni++)                                            \
        acc[mi][ni] = __builtin_amdgcn_mfma_f32_16x16x32_bf16(af[mi], bf[ni], acc[mi][ni], 0, 0, 0); \
    } while (0)

  G2STAGE(0, 0);
  G2STAGE(1, 32);

  for (int k0 = 0; k0 < F_; k0 += 64) {
    int lastp = (k0 + 64 >= F_);
    WAITV4; SB(); SCB();
    { int knext = k0 + 64; G2COMP(0); }
    if (lastp) { WAITV0; } else { WAITV4; }
    SB(); SCB();
    { int knext = k0 + 96; G2COMP(1); }
  }
#undef G2STAGE
#undef G2COMP

#pragma unroll
  for (int mi = 0; mi < 4; mi++)
#pragma unroll
    for (int ni = 0; ni < 4; ni++)
#pragma unroll
      for (int v = 0; v < 4; v++) {
        int row = wm + mi * 16 + quad * 4 + v;
        if (rt * 128 + row < ne) {
          int col = wn + ni * 16 + l15;
          atomicAdd(&out[(size_t)toL[row] + nt * 128 + col], acc[mi][ni][v] * rwL[row]);
        }
      }
}

extern "C" void kernel_launch(void* const* d_in, const int* in_sizes, int n_in,
                              void* d_out, int out_size, void* d_ws, size_t ws_size,
                              hipStream_t stream) {
  const float* x  = (const float*)d_in[0];
  const float* wg = (const float*)d_in[1];
  const float* w1 = (const float*)d_in[2];
  const float* w2 = (const float*)d_in[3];
  float* out = (float*)d_out;

  char* ws = (char*)d_ws;
  int*   counts  = (int*)(ws + 0);
  int*   cursor  = (int*)(ws + 32);
  int*   offs    = (int*)(ws + 64);
  int*   eidx    = (int*)(ws + 128);
  float* ewt     = (float*)(ws + 65664);
  int*   rowlist = (int*)(ws + 131200);
  float* rowwt   = (float*)(ws + 196736);
  unsigned short* g   = (unsigned short*)(ws + 262272);
  unsigned short* xb  = (unsigned short*)(ws + 46399616);
  unsigned short* w1t = (unsigned short*)(ws + 79954048);
  unsigned short* w2t = (unsigned short*)(ws + 172228736);

  hipMemsetAsync(d_out, 0, (size_t)out_size * sizeof(float), stream);
  zero_kernel<<<1, 64, 0, stream>>>((int*)ws);
  cvt_kernel<<<T_ * H_ / 8 / 256, 256, 0, stream>>>(x, xb, T_ * H_ / 8);
  tcvt_kernel<<<dim3(F2_ / 64, H_ / 64, E_), 256, 0, stream>>>(w1, w1t, H_, F2_);
  tcvt_kernel<<<dim3(H_ / 64, F_ / 64, E_), 256, 0, stream>>>(w2, w2t, F_, H_);
  gate_kernel<<<T_ / 4, 256, 0, stream>>>(x, wg, counts, eidx, ewt);
  scan_kernel<<<1, 64, 0, stream>>>(counts, offs);
  assign_kernel<<<T_ / 256, 256, 0, stream>>>(eidx, ewt, offs, cursor, rowlist, rowwt);
  gemm1_kernel<<<dim3(64, 22, E_), 256, 0, stream>>>(xb, w1t, counts, offs, rowlist, g);
  gemm2_kernel<<<dim3(64, 16, E_), 256, 0, stream>>>(g, w2t, counts, offs, rowlist, rowwt, out);
}